// Round 12
// baseline (175.900 us; speedup 1.0000x reference)
//
#include <hip/hip_runtime.h>
#include <hip/hip_bf16.h>
#include <math.h>

#define B_ 8
#define L_ 1024
#define DM 256
#define DI 512
#define HD 32
#define NH 16
#define DS 128
#define CDIM 768
#define NZX 1280
#define CH 256
#define NC 4
#define M_ (B_*L_)
#define EPSV 1e-5f

typedef short bf16x8 __attribute__((ext_vector_type(8)));
typedef float f32x4 __attribute__((ext_vector_type(4)));

#define OFF_ZX   0
#define SZ_ZX    (M_*NZX/2)
#define OFF_XC   (OFF_ZX+SZ_ZX)
#define SZ_XC    (M_*CDIM/2)
#define OFF_DTP  (OFF_XC+SZ_XC)
#define SZ_DTP   (4*M_*NH)
#define OFF_ACS  (OFF_DTP+SZ_DTP)
#define SZ_ACS   (B_*NC*NH*CH)
#define OFF_S0   (OFF_ACS+SZ_ACS)
#define SZ_S0    (B_*NC*CH*CH/2)
#define OFF_ST   (OFF_S0+SZ_S0)
#define SZ_ST    (B_*NC*NH*HD*DS/2)
#define OFF_Y    (OFF_ST+SZ_ST)
#define SZ_Y     (M_*DI/2)
#define OFF_YNB  (OFF_Y+SZ_Y)
#define SZ_YNB   (M_*DI/2)
#define OFF_XBF  (OFF_YNB+SZ_YNB)
#define SZ_XBF   (M_*DM/2)
#define OFF_WBF  (OFF_XBF+SZ_XBF)
#define SZ_WBF   (1296*DM/2)
#define OFF_WOBF (OFF_WBF+SZ_WBF)
#define SZ_WOBF  (DM*DI/2)
#define OFF_GNP  (OFF_WOBF+SZ_WOBF)
#define SZ_GNP   (64*2)
#define OFF_BT   (OFF_GNP+SZ_GNP)
#define SZ_BT    (32*128*256/2)
#define OFF_OUTB (OFF_BT+SZ_BT)
#define SZ_OUTB  (M_*DM/2)

__device__ __forceinline__ ushort f2bf(float v) {
  __hip_bfloat16 h = __float2bfloat16(v);
  return *(ushort*)&h;
}
__device__ __forceinline__ float bf2f(ushort u) {
  return __uint_as_float(((unsigned int)u) << 16);
}
__device__ __forceinline__ float dt_load(const float* __restrict__ dtp, size_t di) {
  float s = dtp[di] + dtp[(size_t)M_*NH + di] + dtp[2*(size_t)M_*NH + di] + dtp[3*(size_t)M_*NH + di];
  return (s > 20.f) ? s : log1pf(expf(s));
}

// async global->LDS, 16B per lane; dest = wave-uniform base + lane*16
__device__ __forceinline__ void gload16(const ushort* g, ushort* l) {
  __builtin_amdgcn_global_load_lds(
      (const __attribute__((address_space(1))) unsigned int*)g,
      (__attribute__((address_space(3))) unsigned int*)l,
      16, 0, 0);
}

// ---------- fused prep: x transpose+cast + dt partials (bias folded), W casts (8x vec), gnp zero ----------
__global__ __launch_bounds__(256) void k_prep(const float* __restrict__ x,
                                              const float* __restrict__ W_in,
                                              const float* __restrict__ W_out,
                                              const float* __restrict__ dt_bias,
                                              ushort* __restrict__ xbf,
                                              ushort* __restrict__ wbf,
                                              ushort* __restrict__ wobf,
                                              float2* __restrict__ gnp,
                                              float* __restrict__ dtp) {
  __shared__ float Ts[64][65];
  __shared__ float Wd[16][65];
  const int bid = blockIdx.x;
  const int t = threadIdx.x;
  if (bid < 512) {
    const int b = bid & 7, rest = bid >> 3;
    const int kt = rest & 3, lt2 = rest >> 2;
    const int k0 = kt*64, l0 = lt2*64;
    for (int i = t; i < 1024; i += 256) {
      int kk = i>>4, lw = i&15;
      float4 v = *(const float4*)&x[(size_t)b*DM*L_ + (size_t)(k0+kk)*L_ + l0 + lw*4];
      Ts[kk][lw*4+0] = v.x; Ts[kk][lw*4+1] = v.y;
      Ts[kk][lw*4+2] = v.z; Ts[kk][lw*4+3] = v.w;
    }
    for (int i = t; i < 1024; i += 256) {
      int h = i>>6, kk = i&63;
      Wd[h][kk] = W_in[(size_t)(NZX+h)*DM + k0+kk];
    }
    __syncthreads();
    for (int i = t; i < 512; i += 256) {
      int mm = i>>3, kg = i&7;
      union { ushort u[8]; uint4 q; } pk;
#pragma unroll
      for (int j = 0; j < 8; ++j) pk.u[j] = f2bf(Ts[kg*8+j][mm]);
      *(uint4*)&xbf[(size_t)(b*L_ + l0+mm)*DM + k0 + kg*8] = pk.q;
    }
    const int h = t&15, lg = t>>4;
    const float bias = (kt == 0) ? dt_bias[h] : 0.f;
#pragma unroll
    for (int c = 0; c < 4; ++c) {
      const int ll = lg + c*16;
      float acc = bias;
#pragma unroll 8
      for (int kk = 0; kk < 64; ++kk) acc += Wd[h][kk]*Ts[kk][ll];
      dtp[(size_t)kt*M_*NH + (size_t)(b*L_ + l0+ll)*NH + h] = acc;
    }
  } else if (bid < 512 + 162) {
    const int i = ((bid-512)*256 + t)*8;      // 162*2048 = 331776 = 1296*DM
    float4 a = *(const float4*)&W_in[i];
    float4 b4 = *(const float4*)&W_in[i+4];
    union { ushort u[8]; uint4 q; } pk;
    pk.u[0]=f2bf(a.x); pk.u[1]=f2bf(a.y); pk.u[2]=f2bf(a.z); pk.u[3]=f2bf(a.w);
    pk.u[4]=f2bf(b4.x); pk.u[5]=f2bf(b4.y); pk.u[6]=f2bf(b4.z); pk.u[7]=f2bf(b4.w);
    *(uint4*)&wbf[i] = pk.q;
  } else if (bid < 512 + 162 + 64) {
    const int i = ((bid-512-162)*256 + t)*8;  // 64*2048 = 131072 = DM*DI
    float4 a = *(const float4*)&W_out[i];
    float4 b4 = *(const float4*)&W_out[i+4];
    union { ushort u[8]; uint4 q; } pk;
    pk.u[0]=f2bf(a.x); pk.u[1]=f2bf(a.y); pk.u[2]=f2bf(a.z); pk.u[3]=f2bf(a.w);
    pk.u[4]=f2bf(b4.x); pk.u[5]=f2bf(b4.y); pk.u[6]=f2bf(b4.z); pk.u[7]=f2bf(b4.w);
    *(uint4*)&wobf[i] = pk.q;
  } else {
    if (t < 64) gnp[t] = make_float2(0.f, 0.f);
  }
}

// ---------- in-proj GEMM (128x128 tile, global_load_lds, dbuf), batch-affine 1D grid ----------
__global__ __launch_bounds__(256) void k_gemm_in_mfma(const ushort* __restrict__ xbf,
                                                      const ushort* __restrict__ wbf,
                                                      ushort* __restrict__ zxb) {
  __shared__ __attribute__((aligned(16))) ushort As[2][128*32];
  __shared__ __attribute__((aligned(16))) ushort Bs[2][128*32];
  const int tid = threadIdx.x;
  const int id = blockIdx.x;
  const int b = id & 7, r8 = id >> 3;
  const int m0 = (b*8 + r8/10)*128, n0 = (r8%10)*128;
  const int wave = tid>>6, lane = tid&63;
  const int lr = lane&15, quad = lane>>4;
  const int rA = lane>>2;
  const int cA = (lane&3)*8;
  f32x4 acc[2][8];
#pragma unroll
  for (int mi=0;mi<2;++mi)
#pragma unroll
    for (int ni=0;ni<8;++ni)
#pragma unroll
      for (int r=0;r<4;++r) acc[mi][ni][r] = 0.f;
  auto STAGE = [&](int buf, int k0) {
#pragma unroll
    for (int j = 0; j < 2; ++j) {
      const int ch = 2*wave + j;
      const int row = ch*16 + rA;
      gload16(xbf + (size_t)(m0+row)*DM + k0 + cA, &As[buf][ch*512]);
      gload16(wbf + (size_t)(n0+row)*DM + k0 + cA, &Bs[buf][ch*512]);
    }
  };
  STAGE(0, 0);
#pragma unroll
  for (int i = 0; i < 8; ++i) {
    __syncthreads();
    if (i < 7) STAGE((i+1)&1, (i+1)*32);
    const int cur = i&1;
    bf16x8 af[2], bfr[8];
    af[0] = *(const bf16x8*)&As[cur][(wave*32+lr)*32 + quad*8];
    af[1] = *(const bf16x8*)&As[cur][(wave*32+16+lr)*32 + quad*8];
#pragma unroll
    for (int ni=0;ni<8;++ni) bfr[ni] = *(const bf16x8*)&Bs[cur][(ni*16+lr)*32 + quad*8];
#pragma unroll
    for (int mi=0;mi<2;++mi)
#pragma unroll
      for (int ni=0;ni<8;++ni)
        acc[mi][ni] = __builtin_amdgcn_mfma_f32_16x16x32_bf16(af[mi], bfr[ni], acc[mi][ni], 0, 0, 0);
  }
#pragma unroll
  for (int mi=0;mi<2;++mi) {
    int m = m0 + wave*32 + mi*16 + quad*4;
#pragma unroll
    for (int ni=0;ni<8;++ni) {
      int n = n0 + ni*16 + lr;
#pragma unroll
      for (int r=0;r<4;++r) zxb[(size_t)(m+r)*NZX + n] = f2bf(acc[mi][ni][r]);
    }
  }
}

// ---------- conv4 + SiLU -> bf16 xcb (+ direct B^T write), 8x j-vectorized ----------
__global__ __launch_bounds__(256) void k_conv(const ushort* __restrict__ zxb,
                                              const float* __restrict__ cw,
                                              const float* __restrict__ cb,
                                              ushort* __restrict__ xcb,
                                              ushort* __restrict__ btg) {
  const int item = blockIdx.x*256 + threadIdx.x;
  const int jg = item % 96;
  const int lchunk = item / 96;
  const int j0 = jg*8;
  const int l0 = (lchunk & 127)*8;
  const int mb = (lchunk >> 7)*1024;
  float4 w[8]; float bias[8];
#pragma unroll
  for (int jj = 0; jj < 8; ++jj) {
    w[jj] = *(const float4*)&cw[(j0+jj)*4];
    bias[jj] = cb[j0+jj];
  }
  bf16x8 v[11];
#pragma unroll
  for (int i = 0; i < 11; ++i) {
    const int ll = l0 - 3 + i;
    if (ll >= 0) v[i] = *(const bf16x8*)(zxb + (size_t)(mb+ll)*NZX + DI + j0);
    else { bf16x8 z = {0,0,0,0,0,0,0,0}; v[i] = z; }
  }
  union { ushort u[8]; uint4 q; } res[8];
#pragma unroll
  for (int i = 0; i < 8; ++i) {
#pragma unroll
    for (int jj = 0; jj < 8; ++jj) {
      float a = bias[jj]
              + w[jj].x*bf2f((ushort)v[i  ][jj])
              + w[jj].y*bf2f((ushort)v[i+1][jj])
              + w[jj].z*bf2f((ushort)v[i+2][jj])
              + w[jj].w*bf2f((ushort)v[i+3][jj]);
      a = a / (1.f + expf(-a));
      res[i].u[jj] = f2bf(a);
    }
    *(uint4*)&xcb[(size_t)(mb+l0+i)*CDIM + j0] = res[i].q;
  }
  if (jg >= 64 && jg < 80) {
    const int bc = (mb >> 10)*NC + (l0 >> 8);
    const int lc = l0 & 255;
#pragma unroll
    for (int jj = 0; jj < 8; ++jj) {
      const int n = j0 + jj - DI;
      union { ushort u[8]; uint4 q; } tp;
#pragma unroll
      for (int i = 0; i < 8; ++i) tp.u[i] = res[i].u[jj];
      *(uint4*)&btg[((size_t)bc*DS + n)*CH + lc] = tp.q;
    }
  }
}

// ---------- merged: S0 lower-tri tiles (diag pre-masked) + chunk states, batch-affine ----------
__global__ __launch_bounds__(256) void k_s0st(const ushort* __restrict__ xcb,
                                              const ushort* __restrict__ btg,
                                              const float* __restrict__ dtp,
                                              const float* __restrict__ A_log,
                                              float* __restrict__ acs_g,
                                              ushort* __restrict__ stb,
                                              ushort* __restrict__ S0b) {
  __shared__ float wtot[4];
  __shared__ ushort Xw[32][264];
  const int id = blockIdx.x;
  const int b = id & 7, r8 = id >> 3;
  const int role = r8 % 26;
  const int bc = b*NC + r8/26;
  const int base = bc*CH;
  const int t = threadIdx.x;
  const int wave = t>>6, lane = t&63, lr = lane&15, quad = lane>>4;
  if (role < 10) {
    const int lt = (role>=6) ? 3 : (role>=3) ? 2 : (role>=1) ? 1 : 0;
    const int st = role - lt*(lt+1)/2;
    const int l = lt*64 + wave*16 + lr;
    f32x4 acc[4];
#pragma unroll
    for (int nt = 0; nt < 4; ++nt)
#pragma unroll
      for (int r = 0; r < 4; ++r) acc[nt][r] = 0.f;
#pragma unroll
    for (int ks = 0; ks < 4; ++ks) {
      bf16x8 af = *(const bf16x8*)(xcb + (size_t)(base+l)*CDIM + (DI+DS) + ks*32 + quad*8);
#pragma unroll
      for (int nt = 0; nt < 4; ++nt) {
        bf16x8 bf = *(const bf16x8*)(xcb + (size_t)(base + st*64 + nt*16 + lr)*CDIM + DI + ks*32 + quad*8);
        acc[nt] = __builtin_amdgcn_mfma_f32_16x16x32_bf16(af, bf, acc[nt], 0, 0, 0);
      }
    }
    const bool diag = (lt == st);
#pragma unroll
    for (int nt = 0; nt < 4; ++nt)
#pragma unroll
      for (int r = 0; r < 4; ++r) {
        const int lrow = lt*64 + wave*16 + quad*4 + r;
        const int scol = st*64 + nt*16 + lr;
        ushort v = (!diag || scol <= lrow) ? f2bf(acc[nt][r]) : (ushort)0;
        S0b[((size_t)bc*CH + lrow)*CH + scol] = v;
      }
    return;
  }
  const int h = role - 10;
  float dt_t = dt_load(dtp, (size_t)(base+t)*NH + h);
  float An = -expf(A_log[h]);
  float v = dt_t * An;
#pragma unroll
  for (int off = 1; off < 64; off <<= 1) {
    float u = __shfl_up(v, off);
    if (lane >= off) v += u;
  }
  if (lane == 63) wtot[wave] = v;
  __syncthreads();
  float pre = 0.f, tot = 0.f;
#pragma unroll
  for (int wj = 0; wj < 4; ++wj) {
    float wv = wtot[wj];
    tot += wv;
    if (wj < wave) pre += wv;
  }
  const float a = v + pre;
  const float alast = tot;
  acs_g[((size_t)bc*NH + h)*CH + t] = a;
  float w = expf(alast - a) * dt_t;
  {
    const ushort* xp = xcb + (size_t)(base+t)*CDIM + h*HD;
    ushort tmp[32];
    *(uint4*)&tmp[0]  = *(const uint4*)(xp);
    *(uint4*)&tmp[8]  = *(const uint4*)(xp+8);
    *(uint4*)&tmp[16] = *(const uint4*)(xp+16);
    *(uint4*)&tmp[24] = *(const uint4*)(xp+24);
#pragma unroll
    for (int p = 0; p < 32; ++p) Xw[p][t] = f2bf(bf2f(tmp[p]) * w);
  }
  __syncthreads();
  f32x4 acc2[2][2];
#pragma unroll
  for (int mt=0;mt<2;++mt)
#pragma unroll
    for (int nt=0;nt<2;++nt)
#pragma unroll
      for (int r=0;r<4;++r) acc2[mt][nt][r] = 0.f;
  const ushort* bp = btg + (size_t)bc*DS*CH;
#pragma unroll
  for (int k0 = 0; k0 < CH; k0 += 32) {
    bf16x8 a0 = *(const bf16x8*)&Xw[lr][k0 + quad*8];
    bf16x8 a1 = *(const bf16x8*)&Xw[16+lr][k0 + quad*8];
    bf16x8 b0 = *(const bf16x8*)(bp + (size_t)(wave*32 + lr)*CH + k0 + quad*8);
    bf16x8 b1 = *(const bf16x8*)(bp + (size_t)(wave*32 + 16 + lr)*CH + k0 + quad*8);
    acc2[0][0] = __builtin_amdgcn_mfma_f32_16x16x32_bf16(a0, b0, acc2[0][0], 0,0,0);
    acc2[0][1] = __builtin_amdgcn_mfma_f32_16x16x32_bf16(a0, b1, acc2[0][1], 0,0,0);
    acc2[1][0] = __builtin_amdgcn_mfma_f32_16x16x32_bf16(a1, b0, acc2[1][0], 0,0,0);
    acc2[1][1] = __builtin_amdgcn_mfma_f32_16x16x32_bf16(a1, b1, acc2[1][1], 0,0,0);
  }
  size_t sb = ((size_t)bc*NH + h)*HD*DS;
#pragma unroll
  for (int mt = 0; mt < 2; ++mt)
#pragma unroll
    for (int nt = 0; nt < 2; ++nt)
#pragma unroll
      for (int r = 0; r < 4; ++r)
        stb[sb + (size_t)(mt*16 + quad*4 + r)*DS + wave*32 + nt*16 + lr] = f2bf(acc2[mt][nt][r]);
}

// ---------- Y = Y_diag + Y_off + D*xs (MFMA), batch-affine 1D grid ----------
__global__ __launch_bounds__(256) void k_y_mfma(const ushort* __restrict__ xcb,
    const float* __restrict__ dtp, const float* __restrict__ acs_g,
    const ushort* __restrict__ S0b, const ushort* __restrict__ stb,
    const float* __restrict__ Dp, ushort* __restrict__ Yb) {
  __shared__ ushort Xt[32][280];
  __shared__ ushort Xs[32][280];
  __shared__ float acs[CH];
  const int t = threadIdx.x;
  const int id = blockIdx.x;
  const int b = id & 7, r8 = id >> 3;
  const int h = r8 % 16;
  const int bc = b*NC + r8/16;
  const int base = bc*CH;
  const int cc = bc & 3, bc4 = bc & ~3;
  acs[t] = acs_g[((size_t)bc*NH + h)*CH + t];
  const float dts_t = dt_load(dtp, (size_t)(base+t)*NH + h);
  ushort tmp[32];
  {
    const ushort* xp = xcb + (size_t)(base+t)*CDIM + h*HD;
    *(uint4*)&tmp[0]  = *(const uint4*)(xp);
    *(uint4*)&tmp[8]  = *(const uint4*)(xp+8);
    *(uint4*)&tmp[16] = *(const uint4*)(xp+16);
    *(uint4*)&tmp[24] = *(const uint4*)(xp+24);
#pragma unroll
    for (int p = 0; p < 32; ++p) Xt[p][t] = tmp[p];
  }
  __syncthreads();
  const float e32 = expf(acs[t & ~31] - acs[t]) * dts_t;
#pragma unroll
  for (int p = 0; p < 32; ++p) Xs[p][t] = f2bf(bf2f(tmp[p]) * e32);
  __syncthreads();
  const int wave = t>>6, lane = t&63, lr = lane&15, quad = lane>>4;
  f32x4 acc[4][2];
#pragma unroll
  for (int mt=0;mt<4;++mt)
#pragma unroll
    for (int nt=0;nt<2;++nt)
#pragma unroll
      for (int r=0;r<4;++r) acc[mt][nt][r] = 0.f;
  if (cc > 0) {
    float fj[3];
    {
      float cum = 0.f;
      for (int j = cc-1; j >= 0; --j) {
        fj[j] = expf(cum);
        cum += acs_g[((size_t)(bc4+j)*NH + h)*CH + (CH-1)];
      }
    }
#pragma unroll
    for (int ks = 0; ks < 4; ++ks) {
      bf16x8 bfr[2];
#pragma unroll
      for (int nt = 0; nt < 2; ++nt) {
        float P[8];
#pragma unroll
        for (int jj = 0; jj < 8; ++jj) P[jj] = 0.f;
        for (int j = 0; j < cc; ++j) {
          bf16x8 sv = *(const bf16x8*)(stb + ((size_t)(bc4+j)*NH + h)*HD*DS
                                       + (size_t)(nt*16+lr)*DS + ks*32 + quad*8);
#pragma unroll
          for (int jj = 0; jj < 8; ++jj) P[jj] += fj[j]*bf2f((ushort)sv[jj]);
        }
        bf16x8 bb;
#pragma unroll
        for (int jj = 0; jj < 8; ++jj) bb[jj] = (short)f2bf(P[jj]);
        bfr[nt] = bb;
      }
#pragma unroll
      for (int mt = 0; mt < 4; ++mt) {
        int l = mt*64 + wave*16 + lr;
        bf16x8 af = *(const bf16x8*)(xcb + (size_t)(base+l)*CDIM + (DI+DS) + ks*32 + quad*8);
        acc[mt][0] = __builtin_amdgcn_mfma_f32_16x16x32_bf16(af, bfr[0], acc[mt][0], 0,0,0);
        acc[mt][1] = __builtin_amdgcn_mfma_f32_16x16x32_bf16(af, bfr[1], acc[mt][1], 0,0,0);
      }
    }
    const float es0 = expf(acs[0]);
#pragma unroll
    for (int mt = 0; mt < 4; ++mt)
#pragma unroll
      for (int nt = 0; nt < 2; ++nt)
#pragma unroll
        for (int r = 0; r < 4; ++r) acc[mt][nt][r] *= es0;
  }
  const int Kw = (12 + wave) >> 1;
  for (int ks = 0; ks <= Kw; ++ks) {
    const int sq = ks*32;
    const bf16x8 xb0 = *(const bf16x8*)&Xs[lr][sq + quad*8];
    const bf16x8 xb1 = *(const bf16x8*)&Xs[16+lr][sq + quad*8];
    const float g = (ks > 0) ? expf(acs[sq] - acs[sq-32]) : 1.f;
#pragma unroll
    for (int mt = 0; mt < 4; ++mt) {
      const int rt = 4*mt + wave;
      if (ks > (rt>>1)) continue;
      if (ks > 0) {
#pragma unroll
        for (int r = 0; r < 4; ++r) { acc[mt][0][r] *= g; acc[mt][1][r] *= g; }
      }
      const int l = mt*64 + wave*16 + lr;
      const bf16x8 sb = *(const bf16x8*)(S0b + ((size_t)bc*CH + l)*CH + sq + quad*8);
      acc[mt][0] = __builtin_amdgcn_mfma_f32_16x16x32_bf16(sb, xb0, acc[mt][0], 0,0,0);
      acc[mt][1] = __builtin_amdgcn_mfma_f32_16x16x32_bf16(sb, xb1, acc[mt][1], 0,0,0);
    }
  }
  const float dph = Dp[h];
#pragma unroll
  for (int mt = 0; mt < 4; ++mt) {
    const int Kmt = (4*mt + wave) >> 1;
    const float aref = acs[32*Kmt];
    const int lb = mt*64 + wave*16 + quad*4;
#pragma unroll
    for (int r = 0; r < 4; ++r) {
      const float e = expf(acs[lb+r] - aref);
#pragma unroll
      for (int nt = 0; nt < 2; ++nt) {
        const int p = nt*16 + lr;
        float xv = bf2f(Xt[p][lb+r]);
        Yb[(size_t)(base+lb+r)*DI + h*HD + p] = f2bf(acc[mt][nt][r]*e + dph*xv);
      }
    }
  }
}

// ---------- gate + RMSNorm, wave-per-row, 512 blocks x 4 iterations ----------
__global__ __launch_bounds__(256) void k_rms(const ushort* __restrict__ zxb,
                                             const ushort* __restrict__ Yb,
                                             const float* __restrict__ rw,
                                             ushort* __restrict__ yn) {
  const int lane = threadIdx.x & 63;
  const int c0 = lane*8;
  float4 w0 = *(const float4*)&rw[c0];
  float4 w1 = *(const float4*)&rw[c0+4];
  const float wv[8] = {w0.x,w0.y,w0.z,w0.w,w1.x,w1.y,w1.z,w1.w};
#pragma unroll
  for (int it = 0; it < 4; ++it) {
    const int id = blockIdx.x*4 + it;        // 2048 row-groups
    const int b = id & 7, r8 = id >> 3;
    const int m = b*1024 + r8*4 + (threadIdx.x>>6);
    bf16x8 zv = *(const bf16x8*)(zxb + (size_t)m*NZX + c0);
    bf16x8 yv = *(const bf16x8*)(Yb  + (size_t)m*DI  + c0);
    float y[8];
    float ss = 0.f;
#pragma unroll
    for (int j = 0; j < 8; ++j) {
      float z = bf2f((ushort)zv[j]);
      y[j] = bf2f((ushort)yv[j]) * z / (1.f + expf(-z));
      ss += y[j]*y[j];
    }
#pragma unroll
    for (int off = 1; off < 64; off <<= 1) ss += __shfl_xor(ss, off);
    const float inv = rsqrtf(ss * (1.f/DI) + EPSV);
    union { ushort u[8]; uint4 q; } pk;
#pragma unroll
    for (int j = 0; j < 8; ++j) pk.u[j] = f2bf(y[j] * inv * wv[j]);
    *(uint4*)(yn + (size_t)m*DI + c0) = pk.q;
  }
}

// ---------- out-proj GEMM (64x128 tile, global_load_lds, dbuf) + GN partials, batch-affine ----------
__global__ __launch_bounds__(256) void k_gemm_out_mfma(const ushort* __restrict__ ynbf,
                                                       const ushort* __restrict__ wobf,
                                                       ushort* __restrict__ outb,
                                                       float2* __restrict__ gnp) {
  __shared__ __attribute__((aligned(16))) ushort As[2][64*32];
  __shared__ __attribute__((aligned(16))) ushort Bs[2][128*32];
  __shared__ float red[4][8];
  const int tid = threadIdx.x;
  const int id = blockIdx.x;
  const int b = id & 7, r8 = id >> 3;
  const int m0 = b*1024 + (r8>>1)*64, n0 = (r8&1)*128;
  const int wave = tid>>6, lane = tid&63;
  const int lr = lane&15, quad = lane>>4;
  const int rA = lane>>2;
  const int cA = (lane&3)*8;
  f32x4 acc[8];
#pragma unroll
  for (int ni=0;ni<8;++ni)
#pragma unroll
    for (int r=0;r<4;++r) acc[ni][r] = 0.f;
  auto STAGE = [&](int buf, int k0) {
    gload16(ynbf + (size_t)(m0 + wave*16 + rA)*DI + k0 + cA, &As[buf][wave*512]);
#pragma unroll
    for (int j = 0; j < 2; ++j) {
      const int ch = 2*wave + j;
      gload16(wobf + (size_t)(n0 + ch*16 + rA)*DI + k0 + cA, &Bs[buf][ch*512]);
    }
  };
  STAGE(0, 0);
#pragma unroll
  for (int i = 0; i < 16; ++i) {
    __syncthreads();
    if (i < 15) STAGE((i+1)&1, (i+1)*32);
    const int cur = i&1;
    bf16x8 af = *(const bf16x8*)&As[cur][(wave*16+lr)*32 + quad*8];
    bf16x8 bfr[8];
#pragma unroll
    for (int ni=0;ni<8;++ni) bfr[ni] = *(const bf16x8*)&Bs[cur][(ni*16+lr)*32 + quad*8];
#pragma unroll
    for (int ni=0;ni<8;++ni)
      acc[ni] = __builtin_amdgcn_mfma_f32_16x16x32_bf16(af, bfr[ni], acc[ni], 0, 0, 0);
  }
  const int l0 = m0 & 1023;
  float sg[4] = {0.f,0.f,0.f,0.f}, sq2[4] = {0.f,0.f,0.f,0.f};
#pragma unroll
  for (int ni=0;ni<8;++ni) {
    int n = n0 + ni*16 + lr;
    union { ushort u[4]; uint2 q; } pk;
#pragma unroll
    for (int r=0;r<4;++r) pk.u[r] = f2bf(acc[ni][r]);
    *(uint2*)&outb[(size_t)b*DM*L_ + (size_t)n*L_ + l0 + wave*16 + quad*4] = pk.q;
    float ps = acc[ni][0]+acc[ni][1]+acc[ni][2]+acc[ni][3];
    float pq = acc[ni][0]*acc[ni][0]+acc[ni][1]*acc[ni][1]
             + acc[ni][2]*acc[ni][2]+acc[ni][3]*acc[ni][3];
    sg[ni>>1] += ps; sq2[ni>>1] += pq;
  }
#pragma unroll
  for (int g = 0; g < 4; ++g)
#pragma unroll
    for (int off = 32; off > 0; off >>= 1) {
      sg[g]  += __shfl_down(sg[g],  off);
      sq2[g] += __shfl_down(sq2[g], off);
    }
  if (lane == 0) {
#pragma unroll
    for (int g = 0; g < 4; ++g) { red[wave][g] = sg[g]; red[wave][4+g] = sq2[g]; }
  }
  __syncthreads();
  if (tid == 0) {
    int g0 = b*8 + (n0>>5);
#pragma unroll
    for (int g = 0; g < 4; ++g) {
      float S = red[0][g]+red[1][g]+red[2][g]+red[3][g];
      float Q = red[0][4+g]+red[1][4+g]+red[2][4+g]+red[3][4+g];
      atomicAdd(&gnp[g0+g].x, S);
      atomicAdd(&gnp[g0+g].y, Q);
    }
  }
}

// ---------- GroupNorm apply + Mish: bf16 in, fp32 out, 512 blocks x 4 channels ----------
__global__ __launch_bounds__(256) void k_gn_apply(const float2* __restrict__ gnp,
                                                  const float* __restrict__ gw,
                                                  const float* __restrict__ gb,
                                                  const ushort* __restrict__ ob,
                                                  float* __restrict__ o) {
  const int t = threadIdx.x;
#pragma unroll
  for (int it = 0; it < 4; ++it) {
    const int id = blockIdx.x*4 + it;        // 2048 (b,ch) rows
    const int b = id & 7, ch = id >> 3;
    float2 p = gnp[b*8 + (ch>>5)];
    const float mean = p.x * (1.f/(32.f*L_));
    const float var  = p.y * (1.f/(32.f*L_)) - mean*mean;
    const float inv  = rsqrtf(var + EPSV);
    const float w = gw[ch], bb = gb[ch];
    size_t base = ((size_t)b*DM + ch) * L_;
    ushort4 v = *(const ushort4*)&ob[base + t*4];
    float r[4] = {bf2f(v.x), bf2f(v.y), bf2f(v.z), bf2f(v.w)};
#pragma unroll
    for (int j = 0; j < 4; ++j) {
      float u = (r[j] - mean) * inv * w + bb;
      float m;
      if (u > 15.f) m = u;
      else {
        float e = expf(u);
        float a = 1.f + e;
        float a2 = a*a;
        m = u * (a2 - 1.f) / (a2 + 1.f);
      }
      r[j] = m;
    }
    *(float4*)&o[base + t*4] = make_float4(r[0], r[1], r[2], r[3]);
  }
}

extern "C" void kernel_launch(void* const* d_in, const int* in_sizes, int n_in,
                              void* d_out, int out_size, void* d_ws, size_t ws_size,
                              hipStream_t stream) {
  const float* x       = (const float*)d_in[0];
  const float* W_in    = (const float*)d_in[1];
  const float* conv_w  = (const float*)d_in[2];
  const float* conv_b  = (const float*)d_in[3];
  const float* dt_bias = (const float*)d_in[4];
  const float* A_log   = (const float*)d_in[5];
  const float* Dp      = (const float*)d_in[6];
  const float* rms_w   = (const float*)d_in[7];
  const float* W_out   = (const float*)d_in[8];
  const float* gn_w    = (const float*)d_in[9];
  const float* gn_b    = (const float*)d_in[10];
  float* out = (float*)d_out;
  float* ws  = (float*)d_ws;

  ushort* zxb   = (ushort*)(ws + OFF_ZX);
  ushort* xcb   = (ushort*)(ws + OFF_XC);
  float*  dtp   = ws + OFF_DTP;
  float*  acs   = ws + OFF_ACS;
  ushort* S0b   = (ushort*)(ws + OFF_S0);
  ushort* stb   = (ushort*)(ws + OFF_ST);
  ushort* Ybb   = (ushort*)(ws + OFF_Y);
  ushort* ynbf  = (ushort*)(ws + OFF_YNB);
  ushort* xbf   = (ushort*)(ws + OFF_XBF);
  ushort* wbf   = (ushort*)(ws + OFF_WBF);
  ushort* wobf  = (ushort*)(ws + OFF_WOBF);
  float2* gnp   = (float2*)(ws + OFF_GNP);
  ushort* btg   = (ushort*)(ws + OFF_BT);
  ushort* outb  = (ushort*)(ws + OFF_OUTB);

  k_prep         <<<dim3(512+162+64+1), 256, 0, stream>>>(x, W_in, W_out, dt_bias,
                                                          xbf, wbf, wobf, gnp, dtp);
  k_gemm_in_mfma <<<dim3(640),  256, 0, stream>>>(xbf, wbf, zxb);
  k_conv         <<<dim3(384),  256, 0, stream>>>(zxb, conv_w, conv_b, xcb, btg);
  k_s0st         <<<dim3(832),  256, 0, stream>>>(xcb, btg, dtp, A_log, acs, stb, S0b);
  k_y_mfma       <<<dim3(512),  256, 0, stream>>>(xcb, dtp, acs, S0b, stb, Dp, Ybb);
  k_rms          <<<dim3(512),  256, 0, stream>>>(zxb, Ybb, rms_w, ynbf);
  k_gemm_out_mfma<<<dim3(256),  256, 0, stream>>>(ynbf, wobf, outb, gnp);
  k_gn_apply     <<<dim3(512),  256, 0, stream>>>(gnp, gn_w, gn_b, outb, out);
}

// Round 13
// 172.821 us; speedup vs baseline: 1.0178x; 1.0178x over previous
//
#include <hip/hip_runtime.h>
#include <hip/hip_bf16.h>
#include <math.h>

#define B_ 8
#define L_ 1024
#define DM 256
#define DI 512
#define HD 32
#define NH 16
#define DS 128
#define CDIM 768
#define NZX 1280
#define CH 256
#define NC 4
#define M_ (B_*L_)
#define EPSV 1e-5f

typedef short bf16x8 __attribute__((ext_vector_type(8)));
typedef float f32x4 __attribute__((ext_vector_type(4)));

#define OFF_ZX   0
#define SZ_ZX    (M_*NZX/2)
#define OFF_XC   (OFF_ZX+SZ_ZX)
#define SZ_XC    (M_*CDIM/2)
#define OFF_DTP  (OFF_XC+SZ_XC)
#define SZ_DTP   (4*M_*NH)
#define OFF_ACS  (OFF_DTP+SZ_DTP)
#define SZ_ACS   (B_*NC*NH*CH)
#define OFF_S0   (OFF_ACS+SZ_ACS)
#define SZ_S0    (B_*NC*CH*CH/2)
#define OFF_ST   (OFF_S0+SZ_S0)
#define SZ_ST    (B_*NC*NH*HD*DS/2)
#define OFF_Y    (OFF_ST+SZ_ST)
#define SZ_Y     (M_*DI/2)
#define OFF_YNB  (OFF_Y+SZ_Y)
#define SZ_YNB   (M_*DI/2)
#define OFF_XBF  (OFF_YNB+SZ_YNB)
#define SZ_XBF   (M_*DM/2)
#define OFF_WBF  (OFF_XBF+SZ_XBF)
#define SZ_WBF   (1296*DM/2)
#define OFF_WOBF (OFF_WBF+SZ_WBF)
#define SZ_WOBF  (DM*DI/2)
#define OFF_GNP  (OFF_WOBF+SZ_WOBF)
#define SZ_GNP   (64*2)
#define OFF_BT   (OFF_GNP+SZ_GNP)
#define SZ_BT    (32*128*256/2)
#define OFF_OUTB (OFF_BT+SZ_BT)
#define SZ_OUTB  (M_*DM/2)

__device__ __forceinline__ ushort f2bf(float v) {
  __hip_bfloat16 h = __float2bfloat16(v);
  return *(ushort*)&h;
}
__device__ __forceinline__ float bf2f(ushort u) {
  return __uint_as_float(((unsigned int)u) << 16);
}
__device__ __forceinline__ float dt_load(const float* __restrict__ dtp, size_t di) {
  float s = dtp[di] + dtp[(size_t)M_*NH + di] + dtp[2*(size_t)M_*NH + di] + dtp[3*(size_t)M_*NH + di];
  return (s > 20.f) ? s : log1pf(expf(s));
}

// async global->LDS, 16B per lane; dest = wave-uniform base + lane*16
__device__ __forceinline__ void gload16(const ushort* g, ushort* l) {
  __builtin_amdgcn_global_load_lds(
      (const __attribute__((address_space(1))) unsigned int*)g,
      (__attribute__((address_space(3))) unsigned int*)l,
      16, 0, 0);
}

// ---------- fused prep: x transpose+cast + dt partials (bias folded), W casts, gnp zero ----------
__global__ __launch_bounds__(256) void k_prep(const float* __restrict__ x,
                                              const float* __restrict__ W_in,
                                              const float* __restrict__ W_out,
                                              const float* __restrict__ dt_bias,
                                              ushort* __restrict__ xbf,
                                              ushort* __restrict__ wbf,
                                              ushort* __restrict__ wobf,
                                              float2* __restrict__ gnp,
                                              float* __restrict__ dtp) {
  __shared__ float Ts[64][65];
  __shared__ float Wd[16][65];
  const int bid = blockIdx.x;
  const int t = threadIdx.x;
  if (bid < 512) {
    const int b = bid & 7, rest = bid >> 3;
    const int kt = rest & 3, lt2 = rest >> 2;
    const int k0 = kt*64, l0 = lt2*64;
    for (int i = t; i < 1024; i += 256) {
      int kk = i>>4, lw = i&15;
      float4 v = *(const float4*)&x[(size_t)b*DM*L_ + (size_t)(k0+kk)*L_ + l0 + lw*4];
      Ts[kk][lw*4+0] = v.x; Ts[kk][lw*4+1] = v.y;
      Ts[kk][lw*4+2] = v.z; Ts[kk][lw*4+3] = v.w;
    }
    for (int i = t; i < 1024; i += 256) {
      int h = i>>6, kk = i&63;
      Wd[h][kk] = W_in[(size_t)(NZX+h)*DM + k0+kk];
    }
    __syncthreads();
    for (int i = t; i < 512; i += 256) {
      int mm = i>>3, kg = i&7;
      union { ushort u[8]; uint4 q; } pk;
#pragma unroll
      for (int j = 0; j < 8; ++j) pk.u[j] = f2bf(Ts[kg*8+j][mm]);
      *(uint4*)&xbf[(size_t)(b*L_ + l0+mm)*DM + k0 + kg*8] = pk.q;
    }
    const int h = t&15, lg = t>>4;
    const float bias = (kt == 0) ? dt_bias[h] : 0.f;
#pragma unroll
    for (int c = 0; c < 4; ++c) {
      const int ll = lg + c*16;
      float acc = bias;
#pragma unroll 8
      for (int kk = 0; kk < 64; ++kk) acc += Wd[h][kk]*Ts[kk][ll];
      dtp[(size_t)kt*M_*NH + (size_t)(b*L_ + l0+ll)*NH + h] = acc;
    }
  } else if (bid < 512 + 1296) {
    int i = (bid-512)*256 + t;
    if (i < 1296*DM) wbf[i] = f2bf(W_in[i]);
  } else if (bid < 512 + 1296 + 512) {
    int i = (bid-512-1296)*256 + t;
    wobf[i] = f2bf(W_out[i]);
  } else {
    if (t < 64) gnp[t] = make_float2(0.f, 0.f);
  }
}

// ---------- in-proj GEMM (128x128 tile, global_load_lds, dbuf), batch-affine 1D grid ----------
__global__ __launch_bounds__(256) void k_gemm_in_mfma(const ushort* __restrict__ xbf,
                                                      const ushort* __restrict__ wbf,
                                                      ushort* __restrict__ zxb) {
  __shared__ __attribute__((aligned(16))) ushort As[2][128*32];
  __shared__ __attribute__((aligned(16))) ushort Bs[2][128*32];
  const int tid = threadIdx.x;
  const int id = blockIdx.x;
  const int b = id & 7, r8 = id >> 3;
  const int m0 = (b*8 + r8/10)*128, n0 = (r8%10)*128;
  const int wave = tid>>6, lane = tid&63;
  const int lr = lane&15, quad = lane>>4;
  const int rA = lane>>2;
  const int cA = (lane&3)*8;
  f32x4 acc[2][8];
#pragma unroll
  for (int mi=0;mi<2;++mi)
#pragma unroll
    for (int ni=0;ni<8;++ni)
#pragma unroll
      for (int r=0;r<4;++r) acc[mi][ni][r] = 0.f;
  auto STAGE = [&](int buf, int k0) {
#pragma unroll
    for (int j = 0; j < 2; ++j) {
      const int ch = 2*wave + j;
      const int row = ch*16 + rA;
      gload16(xbf + (size_t)(m0+row)*DM + k0 + cA, &As[buf][ch*512]);
      gload16(wbf + (size_t)(n0+row)*DM + k0 + cA, &Bs[buf][ch*512]);
    }
  };
  STAGE(0, 0);
#pragma unroll
  for (int i = 0; i < 8; ++i) {
    __syncthreads();
    if (i < 7) STAGE((i+1)&1, (i+1)*32);
    const int cur = i&1;
    bf16x8 af[2], bfr[8];
    af[0] = *(const bf16x8*)&As[cur][(wave*32+lr)*32 + quad*8];
    af[1] = *(const bf16x8*)&As[cur][(wave*32+16+lr)*32 + quad*8];
#pragma unroll
    for (int ni=0;ni<8;++ni) bfr[ni] = *(const bf16x8*)&Bs[cur][(ni*16+lr)*32 + quad*8];
#pragma unroll
    for (int mi=0;mi<2;++mi)
#pragma unroll
      for (int ni=0;ni<8;++ni)
        acc[mi][ni] = __builtin_amdgcn_mfma_f32_16x16x32_bf16(af[mi], bfr[ni], acc[mi][ni], 0, 0, 0);
  }
#pragma unroll
  for (int mi=0;mi<2;++mi) {
    int m = m0 + wave*32 + mi*16 + quad*4;
#pragma unroll
    for (int ni=0;ni<8;++ni) {
      int n = n0 + ni*16 + lr;
#pragma unroll
      for (int r=0;r<4;++r) zxb[(size_t)(m+r)*NZX + n] = f2bf(acc[mi][ni][r]);
    }
  }
}

// ---------- conv4 + SiLU -> bf16 xcb (+ direct B^T write), 8x j-vectorized ----------
// thread = one 8-channel granule x 8 positions: 11x16B loads, 8x16B stores.
__global__ __launch_bounds__(256) void k_conv(const ushort* __restrict__ zxb,
                                              const float* __restrict__ cw,
                                              const float* __restrict__ cb,
                                              ushort* __restrict__ xcb,
                                              ushort* __restrict__ btg) {
  const int item = blockIdx.x*256 + threadIdx.x;   // 98304 items
  const int jg = item % 96;                         // channel granule (8 ch)
  const int lchunk = item / 96;                     // 0..1023 (8 l's each)
  const int j0 = jg*8;
  const int l0 = (lchunk & 127)*8;
  const int mb = (lchunk >> 7)*1024;
  float4 w[8]; float bias[8];
#pragma unroll
  for (int jj = 0; jj < 8; ++jj) {
    w[jj] = *(const float4*)&cw[(j0+jj)*4];
    bias[jj] = cb[j0+jj];
  }
  bf16x8 v[11];
#pragma unroll
  for (int i = 0; i < 11; ++i) {
    const int ll = l0 - 3 + i;
    if (ll >= 0) v[i] = *(const bf16x8*)(zxb + (size_t)(mb+ll)*NZX + DI + j0);
    else { bf16x8 z = {0,0,0,0,0,0,0,0}; v[i] = z; }
  }
  union { ushort u[8]; uint4 q; } res[8];
#pragma unroll
  for (int i = 0; i < 8; ++i) {
#pragma unroll
    for (int jj = 0; jj < 8; ++jj) {
      float a = bias[jj]
              + w[jj].x*bf2f((ushort)v[i  ][jj])
              + w[jj].y*bf2f((ushort)v[i+1][jj])
              + w[jj].z*bf2f((ushort)v[i+2][jj])
              + w[jj].w*bf2f((ushort)v[i+3][jj]);
      a = a / (1.f + expf(-a));
      res[i].u[jj] = f2bf(a);
    }
    *(uint4*)&xcb[(size_t)(mb+l0+i)*CDIM + j0] = res[i].q;
  }
  // B-panel transpose write: channels [DI, DI+DS) -> granules 64..79
  if (jg >= 64 && jg < 80) {
    const int bc = (mb >> 10)*NC + (l0 >> 8);
    const int lc = l0 & 255;
#pragma unroll
    for (int jj = 0; jj < 8; ++jj) {
      const int n = j0 + jj - DI;
      union { ushort u[8]; uint4 q; } tp;
#pragma unroll
      for (int i = 0; i < 8; ++i) tp.u[i] = res[i].u[jj];
      *(uint4*)&btg[((size_t)bc*DS + n)*CH + lc] = tp.q;
    }
  }
}

// ---------- merged: S0 lower-tri tiles (diag pre-masked) + chunk states, batch-affine ----------
__global__ __launch_bounds__(256) void k_s0st(const ushort* __restrict__ xcb,
                                              const ushort* __restrict__ btg,
                                              const float* __restrict__ dtp,
                                              const float* __restrict__ A_log,
                                              float* __restrict__ acs_g,
                                              ushort* __restrict__ stb,
                                              ushort* __restrict__ S0b) {
  __shared__ float wtot[4];
  __shared__ ushort Xw[32][264];
  const int id = blockIdx.x;
  const int b = id & 7, r8 = id >> 3;
  const int role = r8 % 26;
  const int bc = b*NC + r8/26;
  const int base = bc*CH;
  const int t = threadIdx.x;
  const int wave = t>>6, lane = t&63, lr = lane&15, quad = lane>>4;
  if (role < 10) {
    const int lt = (role>=6) ? 3 : (role>=3) ? 2 : (role>=1) ? 1 : 0;
    const int st = role - lt*(lt+1)/2;
    const int l = lt*64 + wave*16 + lr;
    f32x4 acc[4];
#pragma unroll
    for (int nt = 0; nt < 4; ++nt)
#pragma unroll
      for (int r = 0; r < 4; ++r) acc[nt][r] = 0.f;
#pragma unroll
    for (int ks = 0; ks < 4; ++ks) {
      bf16x8 af = *(const bf16x8*)(xcb + (size_t)(base+l)*CDIM + (DI+DS) + ks*32 + quad*8);
#pragma unroll
      for (int nt = 0; nt < 4; ++nt) {
        bf16x8 bf = *(const bf16x8*)(xcb + (size_t)(base + st*64 + nt*16 + lr)*CDIM + DI + ks*32 + quad*8);
        acc[nt] = __builtin_amdgcn_mfma_f32_16x16x32_bf16(af, bf, acc[nt], 0, 0, 0);
      }
    }
    const bool diag = (lt == st);
#pragma unroll
    for (int nt = 0; nt < 4; ++nt)
#pragma unroll
      for (int r = 0; r < 4; ++r) {
        const int lrow = lt*64 + wave*16 + quad*4 + r;
        const int scol = st*64 + nt*16 + lr;
        ushort v = (!diag || scol <= lrow) ? f2bf(acc[nt][r]) : (ushort)0;
        S0b[((size_t)bc*CH + lrow)*CH + scol] = v;
      }
    return;
  }
  const int h = role - 10;
  float dt_t = dt_load(dtp, (size_t)(base+t)*NH + h);
  float An = -expf(A_log[h]);
  float v = dt_t * An;
#pragma unroll
  for (int off = 1; off < 64; off <<= 1) {
    float u = __shfl_up(v, off);
    if (lane >= off) v += u;
  }
  if (lane == 63) wtot[wave] = v;
  __syncthreads();
  float pre = 0.f, tot = 0.f;
#pragma unroll
  for (int wj = 0; wj < 4; ++wj) {
    float wv = wtot[wj];
    tot += wv;
    if (wj < wave) pre += wv;
  }
  const float a = v + pre;
  const float alast = tot;
  acs_g[((size_t)bc*NH + h)*CH + t] = a;
  float w = expf(alast - a) * dt_t;
  {
    const ushort* xp = xcb + (size_t)(base+t)*CDIM + h*HD;
    ushort tmp[32];
    *(uint4*)&tmp[0]  = *(const uint4*)(xp);
    *(uint4*)&tmp[8]  = *(const uint4*)(xp+8);
    *(uint4*)&tmp[16] = *(const uint4*)(xp+16);
    *(uint4*)&tmp[24] = *(const uint4*)(xp+24);
#pragma unroll
    for (int p = 0; p < 32; ++p) Xw[p][t] = f2bf(bf2f(tmp[p]) * w);
  }
  __syncthreads();
  f32x4 acc2[2][2];
#pragma unroll
  for (int mt=0;mt<2;++mt)
#pragma unroll
    for (int nt=0;nt<2;++nt)
#pragma unroll
      for (int r=0;r<4;++r) acc2[mt][nt][r] = 0.f;
  const ushort* bp = btg + (size_t)bc*DS*CH;
#pragma unroll
  for (int k0 = 0; k0 < CH; k0 += 32) {
    bf16x8 a0 = *(const bf16x8*)&Xw[lr][k0 + quad*8];
    bf16x8 a1 = *(const bf16x8*)&Xw[16+lr][k0 + quad*8];
    bf16x8 b0 = *(const bf16x8*)(bp + (size_t)(wave*32 + lr)*CH + k0 + quad*8);
    bf16x8 b1 = *(const bf16x8*)(bp + (size_t)(wave*32 + 16 + lr)*CH + k0 + quad*8);
    acc2[0][0] = __builtin_amdgcn_mfma_f32_16x16x32_bf16(a0, b0, acc2[0][0], 0,0,0);
    acc2[0][1] = __builtin_amdgcn_mfma_f32_16x16x32_bf16(a0, b1, acc2[0][1], 0,0,0);
    acc2[1][0] = __builtin_amdgcn_mfma_f32_16x16x32_bf16(a1, b0, acc2[1][0], 0,0,0);
    acc2[1][1] = __builtin_amdgcn_mfma_f32_16x16x32_bf16(a1, b1, acc2[1][1], 0,0,0);
  }
  size_t sb = ((size_t)bc*NH + h)*HD*DS;
#pragma unroll
  for (int mt = 0; mt < 2; ++mt)
#pragma unroll
    for (int nt = 0; nt < 2; ++nt)
#pragma unroll
      for (int r = 0; r < 4; ++r)
        stb[sb + (size_t)(mt*16 + quad*4 + r)*DS + wave*32 + nt*16 + lr] = f2bf(acc2[mt][nt][r]);
}

// ---------- Y = Y_diag + Y_off + D*xs (MFMA), batch-affine 1D grid ----------
__global__ __launch_bounds__(256) void k_y_mfma(const ushort* __restrict__ xcb,
    const float* __restrict__ dtp, const float* __restrict__ acs_g,
    const ushort* __restrict__ S0b, const ushort* __restrict__ stb,
    const float* __restrict__ Dp, ushort* __restrict__ Yb) {
  __shared__ ushort Xt[32][280];
  __shared__ ushort Xs[32][280];
  __shared__ float acs[CH];
  const int t = threadIdx.x;
  const int id = blockIdx.x;
  const int b = id & 7, r8 = id >> 3;
  const int h = r8 % 16;
  const int bc = b*NC + r8/16;
  const int base = bc*CH;
  const int cc = bc & 3, bc4 = bc & ~3;
  acs[t] = acs_g[((size_t)bc*NH + h)*CH + t];
  const float dts_t = dt_load(dtp, (size_t)(base+t)*NH + h);
  ushort tmp[32];
  {
    const ushort* xp = xcb + (size_t)(base+t)*CDIM + h*HD;
    *(uint4*)&tmp[0]  = *(const uint4*)(xp);
    *(uint4*)&tmp[8]  = *(const uint4*)(xp+8);
    *(uint4*)&tmp[16] = *(const uint4*)(xp+16);
    *(uint4*)&tmp[24] = *(const uint4*)(xp+24);
#pragma unroll
    for (int p = 0; p < 32; ++p) Xt[p][t] = tmp[p];
  }
  __syncthreads();
  const float e32 = expf(acs[t & ~31] - acs[t]) * dts_t;
#pragma unroll
  for (int p = 0; p < 32; ++p) Xs[p][t] = f2bf(bf2f(tmp[p]) * e32);
  __syncthreads();
  const int wave = t>>6, lane = t&63, lr = lane&15, quad = lane>>4;
  f32x4 acc[4][2];
#pragma unroll
  for (int mt=0;mt<4;++mt)
#pragma unroll
    for (int nt=0;nt<2;++nt)
#pragma unroll
      for (int r=0;r<4;++r) acc[mt][nt][r] = 0.f;
  if (cc > 0) {
    float fj[3];
    {
      float cum = 0.f;
      for (int j = cc-1; j >= 0; --j) {
        fj[j] = expf(cum);
        cum += acs_g[((size_t)(bc4+j)*NH + h)*CH + (CH-1)];
      }
    }
#pragma unroll
    for (int ks = 0; ks < 4; ++ks) {
      bf16x8 bfr[2];
#pragma unroll
      for (int nt = 0; nt < 2; ++nt) {
        float P[8];
#pragma unroll
        for (int jj = 0; jj < 8; ++jj) P[jj] = 0.f;
        for (int j = 0; j < cc; ++j) {
          bf16x8 sv = *(const bf16x8*)(stb + ((size_t)(bc4+j)*NH + h)*HD*DS
                                       + (size_t)(nt*16+lr)*DS + ks*32 + quad*8);
#pragma unroll
          for (int jj = 0; jj < 8; ++jj) P[jj] += fj[j]*bf2f((ushort)sv[jj]);
        }
        bf16x8 bb;
#pragma unroll
        for (int jj = 0; jj < 8; ++jj) bb[jj] = (short)f2bf(P[jj]);
        bfr[nt] = bb;
      }
#pragma unroll
      for (int mt = 0; mt < 4; ++mt) {
        int l = mt*64 + wave*16 + lr;
        bf16x8 af = *(const bf16x8*)(xcb + (size_t)(base+l)*CDIM + (DI+DS) + ks*32 + quad*8);
        acc[mt][0] = __builtin_amdgcn_mfma_f32_16x16x32_bf16(af, bfr[0], acc[mt][0], 0,0,0);
        acc[mt][1] = __builtin_amdgcn_mfma_f32_16x16x32_bf16(af, bfr[1], acc[mt][1], 0,0,0);
      }
    }
    const float es0 = expf(acs[0]);
#pragma unroll
    for (int mt = 0; mt < 4; ++mt)
#pragma unroll
      for (int nt = 0; nt < 2; ++nt)
#pragma unroll
        for (int r = 0; r < 4; ++r) acc[mt][nt][r] *= es0;
  }
  const int Kw = (12 + wave) >> 1;
  for (int ks = 0; ks <= Kw; ++ks) {
    const int sq = ks*32;
    const bf16x8 xb0 = *(const bf16x8*)&Xs[lr][sq + quad*8];
    const bf16x8 xb1 = *(const bf16x8*)&Xs[16+lr][sq + quad*8];
    const float g = (ks > 0) ? expf(acs[sq] - acs[sq-32]) : 1.f;
#pragma unroll
    for (int mt = 0; mt < 4; ++mt) {
      const int rt = 4*mt + wave;
      if (ks > (rt>>1)) continue;
      if (ks > 0) {
#pragma unroll
        for (int r = 0; r < 4; ++r) { acc[mt][0][r] *= g; acc[mt][1][r] *= g; }
      }
      const int l = mt*64 + wave*16 + lr;
      const bf16x8 sb = *(const bf16x8*)(S0b + ((size_t)bc*CH + l)*CH + sq + quad*8);
      acc[mt][0] = __builtin_amdgcn_mfma_f32_16x16x32_bf16(sb, xb0, acc[mt][0], 0,0,0);
      acc[mt][1] = __builtin_amdgcn_mfma_f32_16x16x32_bf16(sb, xb1, acc[mt][1], 0,0,0);
    }
  }
  const float dph = Dp[h];
#pragma unroll
  for (int mt = 0; mt < 4; ++mt) {
    const int Kmt = (4*mt + wave) >> 1;
    const float aref = acs[32*Kmt];
    const int lb = mt*64 + wave*16 + quad*4;
#pragma unroll
    for (int r = 0; r < 4; ++r) {
      const float e = expf(acs[lb+r] - aref);
#pragma unroll
      for (int nt = 0; nt < 2; ++nt) {
        const int p = nt*16 + lr;
        float xv = bf2f(Xt[p][lb+r]);
        Yb[(size_t)(base+lb+r)*DI + h*HD + p] = f2bf(acc[mt][nt][r]*e + dph*xv);
      }
    }
  }
}

// ---------- gate + RMSNorm, wave-per-row, batch-affine 1D grid ----------
__global__ __launch_bounds__(256) void k_rms(const ushort* __restrict__ zxb,
                                             const ushort* __restrict__ Yb,
                                             const float* __restrict__ rw,
                                             ushort* __restrict__ yn) {
  const int id = blockIdx.x;
  const int b = id & 7, r8 = id >> 3;
  const int m = b*1024 + r8*4 + (threadIdx.x>>6);
  const int lane = threadIdx.x & 63;
  const int c0 = lane*8;
  bf16x8 zv = *(const bf16x8*)(zxb + (size_t)m*NZX + c0);
  bf16x8 yv = *(const bf16x8*)(Yb  + (size_t)m*DI  + c0);
  float y[8];
  float ss = 0.f;
#pragma unroll
  for (int j = 0; j < 8; ++j) {
    float z = bf2f((ushort)zv[j]);
    y[j] = bf2f((ushort)yv[j]) * z / (1.f + expf(-z));
    ss += y[j]*y[j];
  }
#pragma unroll
  for (int off = 1; off < 64; off <<= 1) ss += __shfl_xor(ss, off);
  const float inv = rsqrtf(ss * (1.f/DI) + EPSV);
  float4 w0 = *(const float4*)&rw[c0];
  float4 w1 = *(const float4*)&rw[c0+4];
  const float wv[8] = {w0.x,w0.y,w0.z,w0.w,w1.x,w1.y,w1.z,w1.w};
  union { ushort u[8]; uint4 q; } pk;
#pragma unroll
  for (int j = 0; j < 8; ++j) pk.u[j] = f2bf(y[j] * inv * wv[j]);
  *(uint4*)(yn + (size_t)m*DI + c0) = pk.q;
}

// ---------- out-proj GEMM (64x128 tile, global_load_lds, dbuf) + GN partials, batch-affine ----------
__global__ __launch_bounds__(256) void k_gemm_out_mfma(const ushort* __restrict__ ynbf,
                                                       const ushort* __restrict__ wobf,
                                                       ushort* __restrict__ outb,
                                                       float2* __restrict__ gnp) {
  __shared__ __attribute__((aligned(16))) ushort As[2][64*32];
  __shared__ __attribute__((aligned(16))) ushort Bs[2][128*32];
  __shared__ float red[4][8];
  const int tid = threadIdx.x;
  const int id = blockIdx.x;
  const int b = id & 7, r8 = id >> 3;
  const int m0 = b*1024 + (r8>>1)*64, n0 = (r8&1)*128;
  const int wave = tid>>6, lane = tid&63;
  const int lr = lane&15, quad = lane>>4;
  const int rA = lane>>2;
  const int cA = (lane&3)*8;
  f32x4 acc[8];
#pragma unroll
  for (int ni=0;ni<8;++ni)
#pragma unroll
    for (int r=0;r<4;++r) acc[ni][r] = 0.f;
  auto STAGE = [&](int buf, int k0) {
    gload16(ynbf + (size_t)(m0 + wave*16 + rA)*DI + k0 + cA, &As[buf][wave*512]);
#pragma unroll
    for (int j = 0; j < 2; ++j) {
      const int ch = 2*wave + j;
      gload16(wobf + (size_t)(n0 + ch*16 + rA)*DI + k0 + cA, &Bs[buf][ch*512]);
    }
  };
  STAGE(0, 0);
#pragma unroll
  for (int i = 0; i < 16; ++i) {
    __syncthreads();
    if (i < 15) STAGE((i+1)&1, (i+1)*32);
    const int cur = i&1;
    bf16x8 af = *(const bf16x8*)&As[cur][(wave*16+lr)*32 + quad*8];
    bf16x8 bfr[8];
#pragma unroll
    for (int ni=0;ni<8;++ni) bfr[ni] = *(const bf16x8*)&Bs[cur][(ni*16+lr)*32 + quad*8];
#pragma unroll
    for (int ni=0;ni<8;++ni)
      acc[ni] = __builtin_amdgcn_mfma_f32_16x16x32_bf16(af, bfr[ni], acc[ni], 0, 0, 0);
  }
  const int l0 = m0 & 1023;
  float sg[4] = {0.f,0.f,0.f,0.f}, sq2[4] = {0.f,0.f,0.f,0.f};
#pragma unroll
  for (int ni=0;ni<8;++ni) {
    int n = n0 + ni*16 + lr;
    union { ushort u[4]; uint2 q; } pk;
#pragma unroll
    for (int r=0;r<4;++r) pk.u[r] = f2bf(acc[ni][r]);
    *(uint2*)&outb[(size_t)b*DM*L_ + (size_t)n*L_ + l0 + wave*16 + quad*4] = pk.q;
    float ps = acc[ni][0]+acc[ni][1]+acc[ni][2]+acc[ni][3];
    float pq = acc[ni][0]*acc[ni][0]+acc[ni][1]*acc[ni][1]
             + acc[ni][2]*acc[ni][2]+acc[ni][3]*acc[ni][3];
    sg[ni>>1] += ps; sq2[ni>>1] += pq;
  }
#pragma unroll
  for (int g = 0; g < 4; ++g)
#pragma unroll
    for (int off = 32; off > 0; off >>= 1) {
      sg[g]  += __shfl_down(sg[g],  off);
      sq2[g] += __shfl_down(sq2[g], off);
    }
  if (lane == 0) {
#pragma unroll
    for (int g = 0; g < 4; ++g) { red[wave][g] = sg[g]; red[wave][4+g] = sq2[g]; }
  }
  __syncthreads();
  if (tid == 0) {
    int g0 = b*8 + (n0>>5);
#pragma unroll
    for (int g = 0; g < 4; ++g) {
      float S = red[0][g]+red[1][g]+red[2][g]+red[3][g];
      float Q = red[0][4+g]+red[1][4+g]+red[2][4+g]+red[3][4+g];
      atomicAdd(&gnp[g0+g].x, S);
      atomicAdd(&gnp[g0+g].y, Q);
    }
  }
}

// ---------- GroupNorm apply + Mish: bf16 in, fp32 out, batch-affine 1D grid ----------
__global__ __launch_bounds__(256) void k_gn_apply(const float2* __restrict__ gnp,
                                                  const float* __restrict__ gw,
                                                  const float* __restrict__ gb,
                                                  const ushort* __restrict__ ob,
                                                  float* __restrict__ o) {
  const int id = blockIdx.x;
  const int b = id & 7, ch = id >> 3;
  const int t = threadIdx.x;
  float2 p = gnp[b*8 + (ch>>5)];
  const float mean = p.x * (1.f/(32.f*L_));
  const float var  = p.y * (1.f/(32.f*L_)) - mean*mean;
  const float inv  = rsqrtf(var + EPSV);
  const float w = gw[ch], bb = gb[ch];
  size_t base = ((size_t)b*DM + ch) * L_;
  ushort4 v = *(const ushort4*)&ob[base + t*4];
  float r[4] = {bf2f(v.x), bf2f(v.y), bf2f(v.z), bf2f(v.w)};
#pragma unroll
  for (int j = 0; j < 4; ++j) {
    float u = (r[j] - mean) * inv * w + bb;
    float m;
    if (u > 15.f) m = u;
    else {
      float e = expf(u);
      float a = 1.f + e;
      float a2 = a*a;
      m = u * (a2 - 1.f) / (a2 + 1.f);
    }
    r[j] = m;
  }
  *(float4*)&o[base + t*4] = make_float4(r[0], r[1], r[2], r[3]);
}

extern "C" void kernel_launch(void* const* d_in, const int* in_sizes, int n_in,
                              void* d_out, int out_size, void* d_ws, size_t ws_size,
                              hipStream_t stream) {
  const float* x       = (const float*)d_in[0];
  const float* W_in    = (const float*)d_in[1];
  const float* conv_w  = (const float*)d_in[2];
  const float* conv_b  = (const float*)d_in[3];
  const float* dt_bias = (const float*)d_in[4];
  const float* A_log   = (const float*)d_in[5];
  const float* Dp      = (const float*)d_in[6];
  const float* rms_w   = (const float*)d_in[7];
  const float* W_out   = (const float*)d_in[8];
  const float* gn_w    = (const float*)d_in[9];
  const float* gn_b    = (const float*)d_in[10];
  float* out = (float*)d_out;
  float* ws  = (float*)d_ws;

  ushort* zxb   = (ushort*)(ws + OFF_ZX);
  ushort* xcb   = (ushort*)(ws + OFF_XC);
  float*  dtp   = ws + OFF_DTP;
  float*  acs   = ws + OFF_ACS;
  ushort* S0b   = (ushort*)(ws + OFF_S0);
  ushort* stb   = (ushort*)(ws + OFF_ST);
  ushort* Ybb   = (ushort*)(ws + OFF_Y);
  ushort* ynbf  = (ushort*)(ws + OFF_YNB);
  ushort* xbf   = (ushort*)(ws + OFF_XBF);
  ushort* wbf   = (ushort*)(ws + OFF_WBF);
  ushort* wobf  = (ushort*)(ws + OFF_WOBF);
  float2* gnp   = (float2*)(ws + OFF_GNP);
  ushort* btg   = (ushort*)(ws + OFF_BT);
  ushort* outb  = (ushort*)(ws + OFF_OUTB);

  k_prep         <<<dim3(512+1296+512+1), 256, 0, stream>>>(x, W_in, W_out, dt_bias,
                                                            xbf, wbf, wobf, gnp, dtp);
  k_gemm_in_mfma <<<dim3(640),  256, 0, stream>>>(xbf, wbf, zxb);
  k_conv         <<<dim3(384),  256, 0, stream>>>(zxb, conv_w, conv_b, xcb, btg);
  k_s0st         <<<dim3(832),  256, 0, stream>>>(xcb, btg, dtp, A_log, acs, stb, S0b);
  k_y_mfma       <<<dim3(512),  256, 0, stream>>>(xcb, dtp, acs, S0b, stb, Dp, Ybb);
  k_rms          <<<dim3(2048), 256, 0, stream>>>(zxb, Ybb, rms_w, ynbf);
  k_gemm_out_mfma<<<dim3(256),  256, 0, stream>>>(ynbf, wobf, outb, gnp);
  k_gn_apply     <<<dim3(2048), 256, 0, stream>>>(gnp, gn_w, gn_b, outb, out);
}